// Round 1
// baseline (285.160 us; speedup 1.0000x reference)
//
#include <hip/hip_runtime.h>

#define S_TOTAL (512 * 512)     // 262144
#define BATCH 64
#define NR 20                   // N_DEG * RANK
#define NBLK_K1 2048
#define S_PER_BLK 128           // S_TOTAL / NBLK_K1  (fits one image row segment)

// ---------------------------------------------------------------------------
// k1: fused bilinear-upsample + za partial dot products.
// 1 wave per block; lane = batch index b. A-addresses depend only on blockIdx
// + loop var -> wave-uniform -> scalar loads (s_load_dwordx4 broadcast).
// partial[blk][nr*64 + b] += A[nr][s] * v[b][s]  over this block's 128 s.
// ---------------------------------------------------------------------------
__global__ __launch_bounds__(64) void za_partial_kernel(
    const float* __restrict__ x,      // (64,1,128,128)
    const float* __restrict__ A,      // (5,4,S) row-major
    float* __restrict__ partial)      // (NBLK_K1, 1280)
{
    const int b   = threadIdx.x;              // lane = batch
    const int blk = blockIdx.x;
    const int s0  = blk * S_PER_BLK;
    const int y   = s0 >> 9;                  // output row (uniform per block)
    const int x0  = s0 & 511;                 // starting output col

    // y-dim bilinear (half-pixel, clamped == jax renormalized edges)
    const float cy  = (y + 0.5f) * 0.25f - 0.5f;
    const int   jy  = (int)floorf(cy);
    const float wy1 = cy - (float)jy;
    const float wy0 = 1.0f - wy1;
    const int   j0  = min(max(jy, 0), 127);
    const int   j1  = min(jy + 1, 127);

    const float* xb   = x + (size_t)b * 16384;   // x[b][0]
    const float* row0 = xb + j0 * 128;
    const float* row1 = xb + j1 * 128;

    float acc[NR];
#pragma unroll
    for (int i = 0; i < NR; ++i) acc[i] = 0.0f;

    const int g0 = x0 >> 2;
    for (int g = 0; g < S_PER_BLK / 4; ++g) {
        const int k  = g0 + g;                // input col center
        const int km = max(k - 1, 0);
        const int kp = min(k + 1, 127);

        const float a0 = row0[km], a1 = row0[k], a2 = row0[kp];
        const float b0 = row1[km], b1 = row1[k], b2 = row1[kp];

        // y-lerp the 3 needed input columns
        const float h0 = a0 * wy0 + b0 * wy1;
        const float h1 = a1 * wy0 + b1 * wy1;
        const float h2 = a2 * wy0 + b2 * wy1;

        // x-dim weights for the 4 phases (exact eighths)
        const float v0 = 0.375f * h0 + 0.625f * h1;
        const float v1 = 0.125f * h0 + 0.875f * h1;
        const float v2 = 0.875f * h1 + 0.125f * h2;
        const float v3 = 0.625f * h1 + 0.375f * h2;

        const int s = s0 + 4 * g;
#pragma unroll
        for (int nr = 0; nr < NR; ++nr) {
            const float4 av = *(const float4*)(A + (size_t)nr * S_TOTAL + s);
            float t = acc[nr];
            t = fmaf(av.x, v0, t);
            t = fmaf(av.y, v1, t);
            t = fmaf(av.z, v2, t);
            t = fmaf(av.w, v3, t);
            acc[nr] = t;
        }
    }

    float* p = partial + (size_t)blk * (NR * 64);
#pragma unroll
    for (int nr = 0; nr < NR; ++nr) p[nr * 64 + b] = acc[nr];   // coalesced
}

// ---------------------------------------------------------------------------
// k2: reduce partials over the 2048 blocks -> za[nr*64 + b]
// ---------------------------------------------------------------------------
__global__ __launch_bounds__(256) void za_reduce_kernel(
    const float* __restrict__ partial, float* __restrict__ za)
{
    const int nr = blockIdx.x;        // 0..19
    const int b  = threadIdx.x & 63;
    const int q  = threadIdx.x >> 6;  // 0..3

    float acc = 0.0f;
    for (int blk = q; blk < NBLK_K1; blk += 4)
        acc += partial[(size_t)blk * (NR * 64) + nr * 64 + b];

    __shared__ float red[4][64];
    red[q][b] = acc;
    __syncthreads();
    if (q == 0)
        za[nr * 64 + b] = red[0][b] + red[1][b] + red[2][b] + red[3][b];
}

// ---------------------------------------------------------------------------
// k3: z recurrence (recomputed per block, cheap) + out = z·C^T + bias
// thread owns 4 consecutive s; loops 64 batches with float4 stores.
// ---------------------------------------------------------------------------
__global__ __launch_bounds__(256) void out_kernel(
    const float* __restrict__ C,      // (S,4)
    const float* __restrict__ bias,   // (S,)
    const float* __restrict__ za,     // (20,64) as nr*64+b
    float* __restrict__ out)          // (64,S)
{
    __shared__ float zs[BATCH][4];
    const int t = threadIdx.x;
    if (t < 64) {
        const int bb = t;
#pragma unroll
        for (int r = 0; r < 4; ++r) {
            float zv = za[r * 64 + bb];              // n = 0
#pragma unroll
            for (int n = 1; n < 5; ++n)
                zv *= (1.0f + za[(n * 4 + r) * 64 + bb]);
            zs[bb][r] = zv;
        }
    }
    __syncthreads();

    const int s0 = (blockIdx.x * 256 + t) * 4;
    const float4 c0 = *(const float4*)(C + (size_t)s0 * 4);
    const float4 c1 = *(const float4*)(C + (size_t)s0 * 4 + 4);
    const float4 c2 = *(const float4*)(C + (size_t)s0 * 4 + 8);
    const float4 c3 = *(const float4*)(C + (size_t)s0 * 4 + 12);
    const float4 bv = *(const float4*)(bias + s0);

#pragma unroll 4
    for (int bb = 0; bb < BATCH; ++bb) {
        const float z0 = zs[bb][0], z1 = zs[bb][1];
        const float z2 = zs[bb][2], z3 = zs[bb][3];
        float4 o;
        o.x = fmaf(z0, c0.x, fmaf(z1, c0.y, fmaf(z2, c0.z, fmaf(z3, c0.w, bv.x))));
        o.y = fmaf(z0, c1.x, fmaf(z1, c1.y, fmaf(z2, c1.z, fmaf(z3, c1.w, bv.y))));
        o.z = fmaf(z0, c2.x, fmaf(z1, c2.y, fmaf(z2, c2.z, fmaf(z3, c2.w, bv.z))));
        o.w = fmaf(z0, c3.x, fmaf(z1, c3.y, fmaf(z2, c3.z, fmaf(z3, c3.w, bv.w))));
        *(float4*)(out + (size_t)bb * S_TOTAL + s0) = o;
    }
}

// ---------------------------------------------------------------------------
extern "C" void kernel_launch(void* const* d_in, const int* in_sizes, int n_in,
                              void* d_out, int out_size, void* d_ws, size_t ws_size,
                              hipStream_t stream)
{
    const float* x    = (const float*)d_in[0];
    const float* A    = (const float*)d_in[1];
    const float* C    = (const float*)d_in[2];
    const float* bias = (const float*)d_in[3];
    float* out = (float*)d_out;

    float* partial = (float*)d_ws;                          // 2048*1280 floats
    float* za      = partial + (size_t)NBLK_K1 * (NR * 64); // 1280 floats

    za_partial_kernel<<<NBLK_K1, 64, 0, stream>>>(x, A, partial);
    za_reduce_kernel<<<NR, 256, 0, stream>>>(partial, za);
    out_kernel<<<S_TOTAL / 4 / 256, 256, 0, stream>>>(C, bias, za, out);
}

// Round 2
// 79.092 us; speedup vs baseline: 3.6054x; 3.6054x over previous
//
#include <hip/hip_runtime.h>

#define S_TOTAL (512 * 512)     // 262144
#define BATCH 64
#define NR 20                   // N_DEG * RANK
#define NBLK_K1 1024            // one half-row (256 s) per block
#define NBLK_K2A 128            // 8 k1-partials each
#define HW 69                   // h row pitch: gcd(69,32)=1 -> conflict-free

// ---------------------------------------------------------------------------
// k1: fused bilinear-upsample + za partials. 256 thr / block.
// Phase 1: stage y-lerped input row h[64][66] and A-tile [20][256] in LDS
//          (all loads vector + coalesced; A no longer touches scalar path).
// Phase 2: lane = batch b; waves split k (16 each); A via uniform ds_read_b128
//          broadcast; acc[20] per lane. Cross-wave reduce via LDS at end.
// ---------------------------------------------------------------------------
__global__ __launch_bounds__(256) void za_partial_kernel(
    const float* __restrict__ x,      // (64,1,128,128)
    const float* __restrict__ A,      // (5,4,S)
    float* __restrict__ partial)      // (NBLK_K1, 1280)
{
    __shared__ float hrow[BATCH][HW];   // 17.7 KB
    __shared__ float ashare[5120];      // A tile [20][256]; reused as red[4][1280]

    const int t    = threadIdx.x;
    const int blk  = blockIdx.x;
    const int y    = blk >> 1;          // output row
    const int half = blk & 1;           // which half of the row
    const int s0   = blk << 8;          // = y*512 + half*256
    const int kst  = half << 6;         // first input col center (0 or 64)

    // y-dim bilinear (half-pixel, clamped == jax renormalized edges)
    const float cy  = (y + 0.5f) * 0.25f - 0.5f;
    const float fj  = floorf(cy);
    const int   jy  = (int)fj;
    const float wy1 = cy - fj;
    const float wy0 = 1.0f - wy1;
    const int   j0  = min(max(jy, 0), 127);
    const int   j1  = min(max(jy + 1, 0), 127);

    // ---- phase 1a: h[b][col] = wy0*x[b][j0][cin] + wy1*x[b][j1][cin]
    // col 0..65 <-> input col kst-1 .. kst+64 (clamped). Coalesced in cin.
    for (int e = t; e < BATCH * 66; e += 256) {
        const int b   = e / 66;
        const int col = e - b * 66;
        const int cin = min(max(kst - 1 + col, 0), 127);
        const float xv0 = x[b * 16384 + j0 * 128 + cin];
        const float xv1 = x[b * 16384 + j1 * 128 + cin];
        hrow[b][col] = xv0 * wy0 + xv1 * wy1;
    }
    // ---- phase 1b: A tile, float4 coalesced. 5 iters x (4 nr-groups x 64 lanes)
    {
        const int lane = t & 63;
        const int grp  = t >> 6;
#pragma unroll
        for (int i = 0; i < 5; ++i) {
            const int nr = i * 4 + grp;
            const float4 av = *(const float4*)(A + (size_t)nr * S_TOTAL + s0 + lane * 4);
            *(float4*)(&ashare[nr * 256 + lane * 4]) = av;
        }
    }
    __syncthreads();

    // ---- phase 2: lane = batch; wave w covers local k in [16w, 16w+16)
    const int w    = t >> 6;
    const int lane = t & 63;

    float acc[NR];
#pragma unroll
    for (int i = 0; i < NR; ++i) acc[i] = 0.0f;

    const int kl0 = 16 * w;
    for (int kl = kl0; kl < kl0 + 16; ++kl) {
        const float h0 = hrow[lane][kl];
        const float h1 = hrow[lane][kl + 1];
        const float h2 = hrow[lane][kl + 2];
        const float v0 = 0.375f * h0 + 0.625f * h1;
        const float v1 = 0.125f * h0 + 0.875f * h1;
        const float v2 = 0.875f * h1 + 0.125f * h2;
        const float v3 = 0.625f * h1 + 0.375f * h2;
#pragma unroll
        for (int nr = 0; nr < NR; ++nr) {
            const float4 av = *(const float4*)(&ashare[nr * 256 + kl * 4]);
            acc[nr] = fmaf(av.x, v0, fmaf(av.y, v1,
                      fmaf(av.z, v2, fmaf(av.w, v3, acc[nr]))));
        }
    }

    __syncthreads();                    // all ashare (A) reads done
    float* red = ashare;                // reuse as red[4][1280]
#pragma unroll
    for (int nr = 0; nr < NR; ++nr)
        red[w * 1280 + nr * 64 + lane] = acc[nr];
    __syncthreads();
    for (int i = t; i < 1280; i += 256)
        partial[(size_t)blk * 1280 + i] =
            red[i] + red[1280 + i] + red[2560 + i] + red[3840 + i];
}

// ---------------------------------------------------------------------------
// k2a: reduce 8 k1-partials per block (coalesced columns)
// ---------------------------------------------------------------------------
__global__ __launch_bounds__(256) void za_reduce1_kernel(
    const float* __restrict__ partial, float* __restrict__ partial2)
{
    const int j = blockIdx.x;
    const int t = threadIdx.x;
    for (int c = t; c < 1280; c += 256) {
        float s = 0.0f;
#pragma unroll
        for (int r = 0; r < 8; ++r)
            s += partial[(size_t)(8 * j + r) * 1280 + c];
        partial2[(size_t)j * 1280 + c] = s;
    }
}

// ---------------------------------------------------------------------------
// k2b: final column sum over 128 rows -> za[1280]
// ---------------------------------------------------------------------------
__global__ __launch_bounds__(256) void za_reduce2_kernel(
    const float* __restrict__ partial2, float* __restrict__ za)
{
    const int c = blockIdx.x * 256 + threadIdx.x;
    float s0 = 0.0f, s1 = 0.0f, s2 = 0.0f, s3 = 0.0f;
    for (int r = 0; r < NBLK_K2A; r += 4) {
        s0 += partial2[(size_t)r * 1280 + c];
        s1 += partial2[(size_t)(r + 1) * 1280 + c];
        s2 += partial2[(size_t)(r + 2) * 1280 + c];
        s3 += partial2[(size_t)(r + 3) * 1280 + c];
    }
    za[c] = (s0 + s1) + (s2 + s3);
}

// ---------------------------------------------------------------------------
// k3: z recurrence + out = z*C^T + bias. 1024 blocks: 256 s-chunks x 4 b-groups.
// ---------------------------------------------------------------------------
__global__ __launch_bounds__(256) void out_kernel(
    const float* __restrict__ C,      // (S,4)
    const float* __restrict__ bias,   // (S,)
    const float* __restrict__ za,     // (20,64)
    float* __restrict__ out)          // (64,S)
{
    __shared__ float zs[BATCH][4];
    const int t  = threadIdx.x;
    const int sb = blockIdx.x >> 2;   // s-chunk
    const int bq = blockIdx.x & 3;    // batch quarter

    if (t < 64) {
        const int bb = t;
#pragma unroll
        for (int r = 0; r < 4; ++r) {
            float zv = za[r * 64 + bb];                 // n = 0
#pragma unroll
            for (int n = 1; n < 5; ++n)
                zv *= (1.0f + za[(n * 4 + r) * 64 + bb]);
            zs[bb][r] = zv;
        }
    }
    __syncthreads();

    const int s0 = (sb * 256 + t) * 4;
    const float4 c0 = *(const float4*)(C + (size_t)s0 * 4);
    const float4 c1 = *(const float4*)(C + (size_t)s0 * 4 + 4);
    const float4 c2 = *(const float4*)(C + (size_t)s0 * 4 + 8);
    const float4 c3 = *(const float4*)(C + (size_t)s0 * 4 + 12);
    const float4 bv = *(const float4*)(bias + s0);

#pragma unroll 4
    for (int bb = bq * 16; bb < bq * 16 + 16; ++bb) {
        const float z0 = zs[bb][0], z1 = zs[bb][1];
        const float z2 = zs[bb][2], z3 = zs[bb][3];
        float4 o;
        o.x = fmaf(z0, c0.x, fmaf(z1, c0.y, fmaf(z2, c0.z, fmaf(z3, c0.w, bv.x))));
        o.y = fmaf(z0, c1.x, fmaf(z1, c1.y, fmaf(z2, c1.z, fmaf(z3, c1.w, bv.y))));
        o.z = fmaf(z0, c2.x, fmaf(z1, c2.y, fmaf(z2, c2.z, fmaf(z3, c2.w, bv.z))));
        o.w = fmaf(z0, c3.x, fmaf(z1, c3.y, fmaf(z2, c3.z, fmaf(z3, c3.w, bv.w))));
        *(float4*)(out + (size_t)bb * S_TOTAL + s0) = o;
    }
}

// ---------------------------------------------------------------------------
extern "C" void kernel_launch(void* const* d_in, const int* in_sizes, int n_in,
                              void* d_out, int out_size, void* d_ws, size_t ws_size,
                              hipStream_t stream)
{
    const float* x    = (const float*)d_in[0];
    const float* A    = (const float*)d_in[1];
    const float* C    = (const float*)d_in[2];
    const float* bias = (const float*)d_in[3];
    float* out = (float*)d_out;

    float* partial  = (float*)d_ws;                          // 1024*1280
    float* partial2 = partial + (size_t)NBLK_K1 * 1280;      // 128*1280
    float* za       = partial2 + (size_t)NBLK_K2A * 1280;    // 1280

    za_partial_kernel<<<NBLK_K1, 256, 0, stream>>>(x, A, partial);
    za_reduce1_kernel<<<NBLK_K2A, 256, 0, stream>>>(partial, partial2);
    za_reduce2_kernel<<<5, 256, 0, stream>>>(partial2, za);
    out_kernel<<<1024, 256, 0, stream>>>(C, bias, za, out);
}